// Round 5
// baseline (296.906 us; speedup 1.0000x reference)
//
#include <hip/hip_runtime.h>
#include <math.h>

#define BS 8192
#define HALF 4096
#define DIM 1024
#define TAU_INV 20.0f
#define BIGP 1.0e10f

typedef __attribute__((ext_vector_type(8))) short bf16x8;
typedef __attribute__((ext_vector_type(4))) float f32x4;

#define GLOAD_LDS16(g, l)                                              \
    __builtin_amdgcn_global_load_lds(                                  \
        (const __attribute__((address_space(1))) void*)(g),            \
        (__attribute__((address_space(3))) void*)(l), 16, 0, 0)

__device__ inline unsigned short f2bf(float f) {
    union { float f; unsigned int u; } c; c.f = f;
    unsigned int u = c.u;
    u += 0x7FFFu + ((u >> 16) & 1u);
    return (unsigned short)(u >> 16);
}

// ---------------------------------------------------------------------------
// 1) Row-normalize concat(f1,f2), convert to bf16, store to ws.
// ---------------------------------------------------------------------------
__global__ __launch_bounds__(256) void norm_kernel(const float* __restrict__ f1,
                                                   const float* __restrict__ f2,
                                                   unsigned short* __restrict__ nb) {
    const int row = blockIdx.x;
    const int t = threadIdx.x;
    const float* src = (row < HALF) ? (f1 + (size_t)row * DIM)
                                    : (f2 + (size_t)(row - HALF) * DIM);
    float4 v = reinterpret_cast<const float4*>(src)[t];
    float ss = v.x * v.x + v.y * v.y + v.z * v.z + v.w * v.w;
#pragma unroll
    for (int off = 32; off > 0; off >>= 1) ss += __shfl_down(ss, off, 64);
    __shared__ float red[4];
    if ((t & 63) == 0) red[t >> 6] = ss;
    __syncthreads();
    float tot = red[0] + red[1] + red[2] + red[3];
    float inv = 1.0f / fmaxf(sqrtf(tot), 1e-8f);
    ushort4 o;
    o.x = f2bf(v.x * inv);
    o.y = f2bf(v.y * inv);
    o.z = f2bf(v.z * inv);
    o.w = f2bf(v.w * inv);
    reinterpret_cast<ushort4*>(nb + (size_t)row * DIM)[t] = o;
}

// ---------------------------------------------------------------------------
// 2) SYMMETRIC S = N*N^T: only upper-triangle blocks (bx >= by), 2080 blocks.
//    m97 structure (global_load_lds w16, linear LDS + both-sides XOR swizzle).
//    Epilogue: direct logits write + exp row-sum partials (psum[bx]) +
//    exp col-sum partials (psum[by], = transposed row-sums) + target extract +
//    transposed tile write via LDS transpose. Diagonal blocks: direct only.
// ---------------------------------------------------------------------------
#define BM 128
#define BN 128
#define BK 64

__global__ __launch_bounds__(256) void gemm_kernel(const unsigned short* __restrict__ nb,
                                                   float* __restrict__ logits,
                                                   float* __restrict__ psum,
                                                   float* __restrict__ targ) {
    __shared__ union {
        struct { unsigned short A[BM][BK]; unsigned short B[BN][BK]; } s;  // 32 KB
        float T[64][129];                                                   // 33 KB
    } smem;
    __shared__ float rowpart[2][BM];
    __shared__ float colpart[2][BM];

    const int t = threadIdx.x;
    const int lane = t & 63;
    const int wid = t >> 6;
    const int wr = wid >> 1;
    const int wc = wid & 1;
    const int lo = lane & 15;
    const int hi = lane >> 4;

    // triangular decode: column-major upper triangle, bx >= by
    const int id = blockIdx.x;
    int bx = (int)((sqrtf(8.0f * (float)id + 1.0f) - 1.0f) * 0.5f);
    while ((bx + 1) * (bx + 2) / 2 <= id) ++bx;
    while (bx * (bx + 1) / 2 > id) --bx;
    const int by = id - bx * (bx + 1) / 2;
    const bool diag = (bx == by);

    const int rowBase = by * BM;
    const int colBase = bx * BN;

    f32x4 acc[4][4];
#pragma unroll
    for (int m = 0; m < 4; ++m)
#pragma unroll
        for (int n = 0; n < 4; ++n) {
            acc[m][n][0] = 0.f; acc[m][n][1] = 0.f;
            acc[m][n][2] = 0.f; acc[m][n][3] = 0.f;
        }

    // staging: LDS(row, cb) holds global (row, cb ^ ((row&7)<<4)) [bytes]
    const int srow = lane >> 3;
    const int skoff = (((lane & 7) ^ srow) << 3);
    const char* Abase = (const char*)&smem.s.A[0][0];
    const char* Bbase = (const char*)&smem.s.B[0][0];
    const int rswz = (lo & 7) << 4;

    for (int kt = 0; kt < DIM; kt += BK) {
#pragma unroll
        for (int i = 0; i < 4; ++i) {
            const int chunk = wid * 4 + i;
            const int r = chunk * 8 + srow;
            const unsigned short* gA = nb + (size_t)(rowBase + r) * DIM + kt + skoff;
            GLOAD_LDS16(gA, (char*)&smem.s.A[0][0] + chunk * 1024);
            const unsigned short* gB = nb + (size_t)(colBase + r) * DIM + kt + skoff;
            GLOAD_LDS16(gB, (char*)&smem.s.B[0][0] + chunk * 1024);
        }
        __syncthreads();

#pragma unroll
        for (int ks = 0; ks < BK; ks += 32) {
            bf16x8 a[4], b[4];
#pragma unroll
            for (int m = 0; m < 4; ++m) {
                const int rr = wr * 64 + m * 16 + lo;
                a[m] = *reinterpret_cast<const bf16x8*>(
                    Abase + rr * 128 + ((ks * 2 + hi * 16) ^ rswz));
            }
#pragma unroll
            for (int n = 0; n < 4; ++n) {
                const int rr = wc * 64 + n * 16 + lo;
                b[n] = *reinterpret_cast<const bf16x8*>(
                    Bbase + rr * 128 + ((ks * 2 + hi * 16) ^ rswz));
            }
#pragma unroll
            for (int m = 0; m < 4; ++m)
#pragma unroll
                for (int n = 0; n < 4; ++n)
                    acc[m][n] = __builtin_amdgcn_mfma_f32_16x16x32_bf16(a[m], b[n], acc[m][n], 0, 0, 0);
        }
        __syncthreads();
    }

    // ---- Epilogue pass 1: direct store + row-sums + col-sums + targets ----
    // C/D mapping: col = lane&15 (+n*16), row = (lane>>4)*4 + reg (+m*16).
    float sums[16];   // per (m,r): row-sum partial over this thread's cols
    float psn[4];     // per n: col-sum partial over this thread's rows
#pragma unroll
    for (int p = 0; p < 16; ++p) sums[p] = 0.f;
#pragma unroll
    for (int n = 0; n < 4; ++n) psn[n] = 0.f;

#pragma unroll
    for (int m = 0; m < 4; ++m) {
#pragma unroll
        for (int n = 0; n < 4; ++n) {
            const int col = colBase + wc * 64 + n * 16 + lo;
#pragma unroll
            for (int r = 0; r < 4; ++r) {
                const int row = rowBase + wr * 64 + m * 16 + hi * 4 + r;
                float v = acc[m][n][r] * TAU_INV;
                if (row == col) v -= BIGP;
                __builtin_nontemporal_store(v, &logits[(size_t)row * BS + col]);
                if (col == row + HALF) { targ[row] = v; targ[col] = v; }
                const float e = __expf(v - 20.0f);  // diag -> 0
                sums[m * 4 + r] += e;
                psn[n] += e;
            }
        }
    }

    // row-sum reduce across the 16-lane col group
    float sel = 0.f;
#pragma unroll
    for (int p = 0; p < 16; ++p) {
        float s = sums[p];
        s += __shfl_xor(s, 1, 64);
        s += __shfl_xor(s, 2, 64);
        s += __shfl_xor(s, 4, 64);
        s += __shfl_xor(s, 8, 64);
        sel = (lo == p) ? s : sel;
    }
    rowpart[wc][wr * 64 + (lo >> 2) * 16 + hi * 4 + (lo & 3)] = sel;

    // col-sum reduce across hi groups (sum over the wave's 64 rows)
    if (!diag) {
        float cs0 = psn[0], cs1 = psn[1], cs2 = psn[2], cs3 = psn[3];
        cs0 += __shfl_xor(cs0, 16, 64); cs0 += __shfl_xor(cs0, 32, 64);
        cs1 += __shfl_xor(cs1, 16, 64); cs1 += __shfl_xor(cs1, 32, 64);
        cs2 += __shfl_xor(cs2, 16, 64); cs2 += __shfl_xor(cs2, 32, 64);
        cs3 += __shfl_xor(cs3, 16, 64); cs3 += __shfl_xor(cs3, 32, 64);
        const float cw = (hi == 0) ? cs0 : (hi == 1) ? cs1 : (hi == 2) ? cs2 : cs3;
        colpart[wr][wc * 64 + hi * 16 + lo] = cw;
    }
    __syncthreads();

    if (t < BM) {
        psum[(size_t)bx * BS + rowBase + t] = rowpart[0][t] + rowpart[1][t];
        if (!diag)
            psum[(size_t)by * BS + colBase + t] = colpart[0][t] + colpart[1][t];
    }

    // ---- Epilogue pass 2: transposed tile write (non-diagonal only) ----
    if (!diag) {
#pragma unroll
        for (int p = 0; p < 2; ++p) {
            __syncthreads();   // previous readers of smem / T done
            if (wc == p) {
#pragma unroll
                for (int m = 0; m < 4; ++m)
#pragma unroll
                    for (int n = 0; n < 4; ++n)
#pragma unroll
                        for (int r = 0; r < 4; ++r) {
                            const int ccol = n * 16 + lo;                        // 0..63
                            const int crow = wr * 64 + m * 16 + hi * 4 + r;      // 0..127
                            smem.T[ccol][crow] = acc[m][n][r] * TAU_INV;
                        }
            }
            __syncthreads();
            const int tr = t >> 2;   // transposed row 0..63
            const int ch = t & 3;
            const float* Trow = &smem.T[tr][0];
            float* gdst = logits + (size_t)(colBase + p * 64 + tr) * BS + rowBase;
#pragma unroll
            for (int j = 0; j < 8; ++j) {
                f32x4 w = *reinterpret_cast<const f32x4*>(&Trow[ch * 4 + j * 16]);
                __builtin_nontemporal_store(w, reinterpret_cast<f32x4*>(&gdst[ch * 4 + j * 16]));
            }
        }
    }
}

// ---------------------------------------------------------------------------
// 3) Per-row: total = sum_cb psum, pe = -(targ - 20 - log total); block
//    partials of w*pe and w; also writes y_true (f32). 32 blocks x 256.
// ---------------------------------------------------------------------------
__global__ __launch_bounds__(256) void reduce_rows_kernel(const float* __restrict__ psum,
                                                          const float* __restrict__ targ,
                                                          const int* __restrict__ mask,
                                                          float* __restrict__ partials,
                                                          float* __restrict__ ytrue_out) {
    const int t = threadIdx.x;
    const int row = blockIdx.x * 256 + t;

    float total = 0.f;
#pragma unroll 8
    for (int cb = 0; cb < 64; ++cb) total += psum[(size_t)cb * BS + row];

    const float pe = -(targ[row] - 20.0f - logf(total));
    const float w = 1.0f - (float)mask[row & (HALF - 1)];
    ytrue_out[row] = (float)((row < HALF) ? row + HALF : row - HALF);

    float a = w * pe, b = w;
#pragma unroll
    for (int off = 32; off > 0; off >>= 1) {
        a += __shfl_down(a, off, 64);
        b += __shfl_down(b, off, 64);
    }
    __shared__ float ra[4], rb[4];
    if ((t & 63) == 0) { ra[t >> 6] = a; rb[t >> 6] = b; }
    __syncthreads();
    if (t == 0) {
        partials[blockIdx.x] = ra[0] + ra[1] + ra[2] + ra[3];
        partials[32 + blockIdx.x] = rb[0] + rb[1] + rb[2] + rb[3];
    }
}

__global__ void loss_kernel(const float* __restrict__ partials,
                            float* __restrict__ loss_out) {
    if (threadIdx.x == 0) {
        float A = 0.f, B = 0.f;
        for (int i = 0; i < 32; ++i) { A += partials[i]; B += partials[32 + i]; }
        loss_out[0] = A / B;
    }
}

// ---------------------------------------------------------------------------
extern "C" void kernel_launch(void* const* d_in, const int* in_sizes, int n_in,
                              void* d_out, int out_size, void* d_ws, size_t ws_size,
                              hipStream_t stream) {
    const float* f1 = (const float*)d_in[0];
    const float* f2 = (const float*)d_in[1];
    const int* mask = (const int*)d_in[2];
    float* out = (float*)d_out;

    unsigned short* nb = (unsigned short*)d_ws;                          // 16 MB
    float* psum = (float*)((char*)d_ws + (size_t)BS * DIM * 2);          // 2 MB
    float* targ = psum + (size_t)64 * BS;                                // 32 KB
    float* partials = targ + BS;                                         // 256 B
    float* logits = out + 1;
    float* ytrue_out = out + 1 + (size_t)BS * BS;

    norm_kernel<<<BS, 256, 0, stream>>>(f1, f2, nb);

    const int ntri = (BS / BM) * (BS / BM + 1) / 2;   // 2080
    gemm_kernel<<<ntri, 256, 0, stream>>>(nb, logits, psum, targ);

    reduce_rows_kernel<<<BS / 256, 256, 0, stream>>>(psum, targ, mask, partials, ytrue_out);
    loss_kernel<<<1, 64, 0, stream>>>(partials, out);
}

// Round 6
// 178.506 us; speedup vs baseline: 1.6633x; 1.6633x over previous
//
#include <hip/hip_runtime.h>
#include <math.h>

#define BS 8192
#define HALF 4096
#define DIM 1024
#define TAU_INV 20.0f
#define BIGP 1.0e10f

typedef __attribute__((ext_vector_type(8))) short bf16x8;
typedef __attribute__((ext_vector_type(4))) float f32x4;

#define GLOAD_LDS16(g, l)                                              \
    __builtin_amdgcn_global_load_lds(                                  \
        (const __attribute__((address_space(1))) void*)(g),            \
        (__attribute__((address_space(3))) void*)(l), 16, 0, 0)

__device__ inline unsigned short f2bf(float f) {
    union { float f; unsigned int u; } c; c.f = f;
    unsigned int u = c.u;
    u += 0x7FFFu + ((u >> 16) & 1u);
    return (unsigned short)(u >> 16);
}

// ---------------------------------------------------------------------------
// 1) Row-normalize concat(f1,f2), convert to bf16, store to ws.
// ---------------------------------------------------------------------------
__global__ __launch_bounds__(256) void norm_kernel(const float* __restrict__ f1,
                                                   const float* __restrict__ f2,
                                                   unsigned short* __restrict__ nb) {
    const int row = blockIdx.x;
    const int t = threadIdx.x;
    const float* src = (row < HALF) ? (f1 + (size_t)row * DIM)
                                    : (f2 + (size_t)(row - HALF) * DIM);
    float4 v = reinterpret_cast<const float4*>(src)[t];
    float ss = v.x * v.x + v.y * v.y + v.z * v.z + v.w * v.w;
#pragma unroll
    for (int off = 32; off > 0; off >>= 1) ss += __shfl_down(ss, off, 64);
    __shared__ float red[4];
    if ((t & 63) == 0) red[t >> 6] = ss;
    __syncthreads();
    float tot = red[0] + red[1] + red[2] + red[3];
    float inv = 1.0f / fmaxf(sqrtf(tot), 1e-8f);
    ushort4 o;
    o.x = f2bf(v.x * inv);
    o.y = f2bf(v.y * inv);
    o.z = f2bf(v.z * inv);
    o.w = f2bf(v.w * inv);
    reinterpret_cast<ushort4*>(nb + (size_t)row * DIM)[t] = o;
}

// ---------------------------------------------------------------------------
// 2) SYMMETRIC S = N*N^T: only upper-triangle blocks (bx >= by), 2080 blocks.
//    m97 structure (global_load_lds w16, linear LDS + both-sides XOR swizzle).
//    Epilogue: direct logits write + exp row-sum partials (psum[bx]) +
//    exp col-sum partials (psum[by]) + target extract + transposed tile write
//    via LDS transpose. Plain stores everywhere — L2 merges 64B halves into
//    full lines (round-3 evidence); NT streaming caused 2x write amplification
//    (round-5 evidence: WRITE 500 MB, RMW FETCH +75 MB).
// ---------------------------------------------------------------------------
#define BM 128
#define BN 128
#define BK 64

__global__ __launch_bounds__(256) void gemm_kernel(const unsigned short* __restrict__ nb,
                                                   float* __restrict__ logits,
                                                   float* __restrict__ psum,
                                                   float* __restrict__ targ) {
    __shared__ union {
        struct { unsigned short A[BM][BK]; unsigned short B[BN][BK]; } s;  // 32 KB
        float T[64][129];                                                   // 33 KB
    } smem;
    __shared__ float rowpart[2][BM];
    __shared__ float colpart[2][BM];

    const int t = threadIdx.x;
    const int lane = t & 63;
    const int wid = t >> 6;
    const int wr = wid >> 1;
    const int wc = wid & 1;
    const int lo = lane & 15;
    const int hi = lane >> 4;

    // triangular decode: column-major upper triangle, bx >= by
    const int id = blockIdx.x;
    int bx = (int)((sqrtf(8.0f * (float)id + 1.0f) - 1.0f) * 0.5f);
    while ((bx + 1) * (bx + 2) / 2 <= id) ++bx;
    while (bx * (bx + 1) / 2 > id) --bx;
    const int by = id - bx * (bx + 1) / 2;
    const bool diag = (bx == by);

    const int rowBase = by * BM;
    const int colBase = bx * BN;

    f32x4 acc[4][4];
#pragma unroll
    for (int m = 0; m < 4; ++m)
#pragma unroll
        for (int n = 0; n < 4; ++n) {
            acc[m][n][0] = 0.f; acc[m][n][1] = 0.f;
            acc[m][n][2] = 0.f; acc[m][n][3] = 0.f;
        }

    // staging: LDS(row, cb) holds global (row, cb ^ ((row&7)<<4)) [bytes]
    const int srow = lane >> 3;
    const int skoff = (((lane & 7) ^ srow) << 3);
    const char* Abase = (const char*)&smem.s.A[0][0];
    const char* Bbase = (const char*)&smem.s.B[0][0];
    const int rswz = (lo & 7) << 4;

    for (int kt = 0; kt < DIM; kt += BK) {
#pragma unroll
        for (int i = 0; i < 4; ++i) {
            const int chunk = wid * 4 + i;
            const int r = chunk * 8 + srow;
            const unsigned short* gA = nb + (size_t)(rowBase + r) * DIM + kt + skoff;
            GLOAD_LDS16(gA, (char*)&smem.s.A[0][0] + chunk * 1024);
            const unsigned short* gB = nb + (size_t)(colBase + r) * DIM + kt + skoff;
            GLOAD_LDS16(gB, (char*)&smem.s.B[0][0] + chunk * 1024);
        }
        __syncthreads();

#pragma unroll
        for (int ks = 0; ks < BK; ks += 32) {
            bf16x8 a[4], b[4];
#pragma unroll
            for (int m = 0; m < 4; ++m) {
                const int rr = wr * 64 + m * 16 + lo;
                a[m] = *reinterpret_cast<const bf16x8*>(
                    Abase + rr * 128 + ((ks * 2 + hi * 16) ^ rswz));
            }
#pragma unroll
            for (int n = 0; n < 4; ++n) {
                const int rr = wc * 64 + n * 16 + lo;
                b[n] = *reinterpret_cast<const bf16x8*>(
                    Bbase + rr * 128 + ((ks * 2 + hi * 16) ^ rswz));
            }
#pragma unroll
            for (int m = 0; m < 4; ++m)
#pragma unroll
                for (int n = 0; n < 4; ++n)
                    acc[m][n] = __builtin_amdgcn_mfma_f32_16x16x32_bf16(a[m], b[n], acc[m][n], 0, 0, 0);
        }
        __syncthreads();
    }

    // ---- Epilogue pass 1: direct store + row-sums + col-sums + targets ----
    // C/D mapping: col = lane&15 (+n*16), row = (lane>>4)*4 + reg (+m*16).
    float sums[16];   // per (m,r): row-sum partial over this thread's cols
    float psn[4];     // per n: col-sum partial over this thread's rows
#pragma unroll
    for (int p = 0; p < 16; ++p) sums[p] = 0.f;
#pragma unroll
    for (int n = 0; n < 4; ++n) psn[n] = 0.f;

#pragma unroll
    for (int m = 0; m < 4; ++m) {
#pragma unroll
        for (int n = 0; n < 4; ++n) {
            const int col = colBase + wc * 64 + n * 16 + lo;
#pragma unroll
            for (int r = 0; r < 4; ++r) {
                const int row = rowBase + wr * 64 + m * 16 + hi * 4 + r;
                float v = acc[m][n][r] * TAU_INV;
                if (row == col) v -= BIGP;
                logits[(size_t)row * BS + col] = v;
                if (col == row + HALF) { targ[row] = v; targ[col] = v; }
                const float e = __expf(v - 20.0f);  // diag -> 0
                sums[m * 4 + r] += e;
                psn[n] += e;
            }
        }
    }

    // row-sum reduce across the 16-lane col group
    float sel = 0.f;
#pragma unroll
    for (int p = 0; p < 16; ++p) {
        float s = sums[p];
        s += __shfl_xor(s, 1, 64);
        s += __shfl_xor(s, 2, 64);
        s += __shfl_xor(s, 4, 64);
        s += __shfl_xor(s, 8, 64);
        sel = (lo == p) ? s : sel;
    }
    rowpart[wc][wr * 64 + (lo >> 2) * 16 + hi * 4 + (lo & 3)] = sel;

    // col-sum reduce across hi groups (sum over the wave's 64 rows)
    if (!diag) {
        float cs0 = psn[0], cs1 = psn[1], cs2 = psn[2], cs3 = psn[3];
        cs0 += __shfl_xor(cs0, 16, 64); cs0 += __shfl_xor(cs0, 32, 64);
        cs1 += __shfl_xor(cs1, 16, 64); cs1 += __shfl_xor(cs1, 32, 64);
        cs2 += __shfl_xor(cs2, 16, 64); cs2 += __shfl_xor(cs2, 32, 64);
        cs3 += __shfl_xor(cs3, 16, 64); cs3 += __shfl_xor(cs3, 32, 64);
        const float cw = (hi == 0) ? cs0 : (hi == 1) ? cs1 : (hi == 2) ? cs2 : cs3;
        colpart[wr][wc * 64 + hi * 16 + lo] = cw;
    }
    __syncthreads();

    if (t < BM) {
        psum[(size_t)bx * BS + rowBase + t] = rowpart[0][t] + rowpart[1][t];
        if (!diag)
            psum[(size_t)by * BS + colBase + t] = colpart[0][t] + colpart[1][t];
    }

    // ---- Epilogue pass 2: transposed tile write (non-diagonal only) ----
    if (!diag) {
#pragma unroll
        for (int p = 0; p < 2; ++p) {
            __syncthreads();   // previous readers of smem / T done
            if (wc == p) {
#pragma unroll
                for (int m = 0; m < 4; ++m)
#pragma unroll
                    for (int n = 0; n < 4; ++n)
#pragma unroll
                        for (int r = 0; r < 4; ++r) {
                            const int ccol = n * 16 + lo;                        // 0..63
                            const int crow = wr * 64 + m * 16 + hi * 4 + r;      // 0..127
                            smem.T[ccol][crow] = acc[m][n][r] * TAU_INV;
                        }
            }
            __syncthreads();
            const int tr = t >> 2;   // transposed row 0..63
            const int ch = t & 3;
            const float* Trow = &smem.T[tr][0];
            float* gdst = logits + (size_t)(colBase + p * 64 + tr) * BS + rowBase;
#pragma unroll
            for (int j = 0; j < 8; ++j) {
                f32x4 w = *reinterpret_cast<const f32x4*>(&Trow[ch * 4 + j * 16]);
                *reinterpret_cast<f32x4*>(&gdst[ch * 4 + j * 16]) = w;
            }
        }
    }
}

// ---------------------------------------------------------------------------
// 3) Per-row: total = sum_cb psum, pe = -(targ - 20 - log total); block
//    partials of w*pe and w; also writes y_true (f32). 32 blocks x 256.
// ---------------------------------------------------------------------------
__global__ __launch_bounds__(256) void reduce_rows_kernel(const float* __restrict__ psum,
                                                          const float* __restrict__ targ,
                                                          const int* __restrict__ mask,
                                                          float* __restrict__ partials,
                                                          float* __restrict__ ytrue_out) {
    const int t = threadIdx.x;
    const int row = blockIdx.x * 256 + t;

    float total = 0.f;
#pragma unroll 8
    for (int cb = 0; cb < 64; ++cb) total += psum[(size_t)cb * BS + row];

    const float pe = -(targ[row] - 20.0f - logf(total));
    const float w = 1.0f - (float)mask[row & (HALF - 1)];
    ytrue_out[row] = (float)((row < HALF) ? row + HALF : row - HALF);

    float a = w * pe, b = w;
#pragma unroll
    for (int off = 32; off > 0; off >>= 1) {
        a += __shfl_down(a, off, 64);
        b += __shfl_down(b, off, 64);
    }
    __shared__ float ra[4], rb[4];
    if ((t & 63) == 0) { ra[t >> 6] = a; rb[t >> 6] = b; }
    __syncthreads();
    if (t == 0) {
        partials[blockIdx.x] = ra[0] + ra[1] + ra[2] + ra[3];
        partials[32 + blockIdx.x] = rb[0] + rb[1] + rb[2] + rb[3];
    }
}

__global__ void loss_kernel(const float* __restrict__ partials,
                            float* __restrict__ loss_out) {
    if (threadIdx.x == 0) {
        float A = 0.f, B = 0.f;
        for (int i = 0; i < 32; ++i) { A += partials[i]; B += partials[32 + i]; }
        loss_out[0] = A / B;
    }
}

// ---------------------------------------------------------------------------
extern "C" void kernel_launch(void* const* d_in, const int* in_sizes, int n_in,
                              void* d_out, int out_size, void* d_ws, size_t ws_size,
                              hipStream_t stream) {
    const float* f1 = (const float*)d_in[0];
    const float* f2 = (const float*)d_in[1];
    const int* mask = (const int*)d_in[2];
    float* out = (float*)d_out;

    unsigned short* nb = (unsigned short*)d_ws;                          // 16 MB
    float* psum = (float*)((char*)d_ws + (size_t)BS * DIM * 2);          // 2 MB
    float* targ = psum + (size_t)64 * BS;                                // 32 KB
    float* partials = targ + BS;                                         // 256 B
    float* logits = out + 1;
    float* ytrue_out = out + 1 + (size_t)BS * BS;

    norm_kernel<<<BS, 256, 0, stream>>>(f1, f2, nb);

    const int ntri = (BS / BM) * (BS / BM + 1) / 2;   // 2080
    gemm_kernel<<<ntri, 256, 0, stream>>>(nb, logits, psum, targ);

    reduce_rows_kernel<<<BS / 256, 256, 0, stream>>>(psum, targ, mask, partials, ytrue_out);
    loss_kernel<<<1, 64, 0, stream>>>(partials, out);
}

// Round 7
// 170.900 us; speedup vs baseline: 1.7373x; 1.0445x over previous
//
#include <hip/hip_runtime.h>
#include <math.h>

#define BS 8192
#define HALF 4096
#define DIM 1024
#define BIGP 1.0e10f
#define SQRT_TAU_INV 4.472135955f  // sqrt(20): prescale both operands -> acc = sim/tau

typedef __attribute__((ext_vector_type(8))) short bf16x8;
typedef __attribute__((ext_vector_type(4))) float f32x4;

#define GLOAD_LDS16(g, l)                                              \
    __builtin_amdgcn_global_load_lds(                                  \
        (const __attribute__((address_space(1))) void*)(g),            \
        (__attribute__((address_space(3))) void*)(l), 16, 0, 0)

__device__ inline unsigned short f2bf(float f) {
    union { float f; unsigned int u; } c; c.f = f;
    unsigned int u = c.u;
    u += 0x7FFFu + ((u >> 16) & 1u);
    return (unsigned short)(u >> 16);
}

// ---------------------------------------------------------------------------
// 1) Row-normalize concat(f1,f2), scale by sqrt(1/tau), convert to bf16.
// ---------------------------------------------------------------------------
__global__ __launch_bounds__(256) void norm_kernel(const float* __restrict__ f1,
                                                   const float* __restrict__ f2,
                                                   unsigned short* __restrict__ nb) {
    const int row = blockIdx.x;
    const int t = threadIdx.x;
    const float* src = (row < HALF) ? (f1 + (size_t)row * DIM)
                                    : (f2 + (size_t)(row - HALF) * DIM);
    float4 v = reinterpret_cast<const float4*>(src)[t];
    float ss = v.x * v.x + v.y * v.y + v.z * v.z + v.w * v.w;
#pragma unroll
    for (int off = 32; off > 0; off >>= 1) ss += __shfl_down(ss, off, 64);
    __shared__ float red[4];
    if ((t & 63) == 0) red[t >> 6] = ss;
    __syncthreads();
    float tot = red[0] + red[1] + red[2] + red[3];
    float inv = SQRT_TAU_INV / fmaxf(sqrtf(tot), 1e-8f);
    ushort4 o;
    o.x = f2bf(v.x * inv);
    o.y = f2bf(v.y * inv);
    o.z = f2bf(v.z * inv);
    o.w = f2bf(v.w * inv);
    reinterpret_cast<ushort4*>(nb + (size_t)row * DIM)[t] = o;
}

// ---------------------------------------------------------------------------
// 2) SYMMETRIC S/tau = N'*N'^T: upper-triangle blocks (bx >= by), 2080 blocks.
//    m97 K-loop (global_load_lds w16, linear LDS + both-sides XOR swizzle).
//    Epilogue (barrier-light): direct scalar store + exp row/col-sum partials
//    + target extract, then transposed tile REGISTER-DIRECT f32x4 stores
//    (acc[m][n][0..3] = 4 consecutive rows = 4 consecutive transposed cols).
// ---------------------------------------------------------------------------
#define BM 128
#define BN 128
#define BK 64

__global__ __launch_bounds__(256) void gemm_kernel(const unsigned short* __restrict__ nb,
                                                   float* __restrict__ logits,
                                                   float* __restrict__ psum,
                                                   float* __restrict__ targ) {
    __shared__ unsigned short As[BM][BK];   // 16 KB
    __shared__ unsigned short Bs[BN][BK];   // 16 KB
    __shared__ float rowpart[2][BM];
    __shared__ float colpart[2][BM];

    const int t = threadIdx.x;
    const int lane = t & 63;
    const int wid = t >> 6;
    const int wr = wid >> 1;
    const int wc = wid & 1;
    const int lo = lane & 15;
    const int hi = lane >> 4;

    // triangular decode: column-major upper triangle, bx >= by
    const int id = blockIdx.x;
    int bx = (int)((sqrtf(8.0f * (float)id + 1.0f) - 1.0f) * 0.5f);
    while ((bx + 1) * (bx + 2) / 2 <= id) ++bx;
    while (bx * (bx + 1) / 2 > id) --bx;
    const int by = id - bx * (bx + 1) / 2;
    const bool diag = (bx == by);

    const int rowBase = by * BM;
    const int colBase = bx * BN;

    f32x4 acc[4][4];
#pragma unroll
    for (int m = 0; m < 4; ++m)
#pragma unroll
        for (int n = 0; n < 4; ++n) {
            acc[m][n][0] = 0.f; acc[m][n][1] = 0.f;
            acc[m][n][2] = 0.f; acc[m][n][3] = 0.f;
        }

    // staging: LDS(row, cb) holds global (row, cb ^ ((row&7)<<4)) [bytes]
    const int srow = lane >> 3;
    const int skoff = (((lane & 7) ^ srow) << 3);
    const char* Abase = (const char*)&As[0][0];
    const char* Bbase = (const char*)&Bs[0][0];
    const int rswz = (lo & 7) << 4;

    for (int kt = 0; kt < DIM; kt += BK) {
#pragma unroll
        for (int i = 0; i < 4; ++i) {
            const int chunk = wid * 4 + i;
            const int r = chunk * 8 + srow;
            const unsigned short* gA = nb + (size_t)(rowBase + r) * DIM + kt + skoff;
            GLOAD_LDS16(gA, (char*)&As[0][0] + chunk * 1024);
            const unsigned short* gB = nb + (size_t)(colBase + r) * DIM + kt + skoff;
            GLOAD_LDS16(gB, (char*)&Bs[0][0] + chunk * 1024);
        }
        __syncthreads();

#pragma unroll
        for (int ks = 0; ks < BK; ks += 32) {
            bf16x8 a[4], b[4];
#pragma unroll
            for (int m = 0; m < 4; ++m) {
                const int rr = wr * 64 + m * 16 + lo;
                a[m] = *reinterpret_cast<const bf16x8*>(
                    Abase + rr * 128 + ((ks * 2 + hi * 16) ^ rswz));
            }
#pragma unroll
            for (int n = 0; n < 4; ++n) {
                const int rr = wc * 64 + n * 16 + lo;
                b[n] = *reinterpret_cast<const bf16x8*>(
                    Bbase + rr * 128 + ((ks * 2 + hi * 16) ^ rswz));
            }
#pragma unroll
            for (int m = 0; m < 4; ++m)
#pragma unroll
                for (int n = 0; n < 4; ++n)
                    acc[m][n] = __builtin_amdgcn_mfma_f32_16x16x32_bf16(a[m], b[n], acc[m][n], 0, 0, 0);
        }
        __syncthreads();
    }

    // ---- Epilogue pass 1: direct store + row-sums + col-sums + targets ----
    // C/D mapping: col = lane&15 (+n*16), row = (lane>>4)*4 + reg (+m*16).
    float sums[16];   // per (m,r): row-sum partial over this thread's cols
    float psn[4];     // per n: col-sum partial over this thread's rows
#pragma unroll
    for (int p = 0; p < 16; ++p) sums[p] = 0.f;
#pragma unroll
    for (int n = 0; n < 4; ++n) psn[n] = 0.f;

#pragma unroll
    for (int m = 0; m < 4; ++m) {
#pragma unroll
        for (int n = 0; n < 4; ++n) {
            const int col = colBase + wc * 64 + n * 16 + lo;
#pragma unroll
            for (int r = 0; r < 4; ++r) {
                const int row = rowBase + wr * 64 + m * 16 + hi * 4 + r;
                float v = acc[m][n][r];
                if (row == col) v -= BIGP;
                logits[(size_t)row * BS + col] = v;
                if (col == row + HALF) { targ[row] = v; targ[col] = v; }
                const float e = __expf(v - 20.0f);  // diag -> 0
                sums[m * 4 + r] += e;
                psn[n] += e;
            }
        }
    }

    // ---- Epilogue pass 2: transposed tile, register-direct f32x4 stores ----
    // acc[m][n][0..3] = rows (base..base+3) at col => transposed: 4 contiguous
    // elements of row `col`. No diagonal in strictly-upper blocks.
    if (!diag) {
#pragma unroll
        for (int m = 0; m < 4; ++m) {
            const int trow0 = rowBase + wr * 64 + m * 16 + hi * 4;
#pragma unroll
            for (int n = 0; n < 4; ++n) {
                const int col = colBase + wc * 64 + n * 16 + lo;
                *reinterpret_cast<f32x4*>(&logits[(size_t)col * BS + trow0]) = acc[m][n];
            }
        }
    }

    // row-sum reduce across the 16-lane col group
    float sel = 0.f;
#pragma unroll
    for (int p = 0; p < 16; ++p) {
        float s = sums[p];
        s += __shfl_xor(s, 1, 64);
        s += __shfl_xor(s, 2, 64);
        s += __shfl_xor(s, 4, 64);
        s += __shfl_xor(s, 8, 64);
        sel = (lo == p) ? s : sel;
    }
    rowpart[wc][wr * 64 + (lo >> 2) * 16 + hi * 4 + (lo & 3)] = sel;

    // col-sum reduce across hi groups (sum over the wave's 64 rows)
    if (!diag) {
        float cs0 = psn[0], cs1 = psn[1], cs2 = psn[2], cs3 = psn[3];
        cs0 += __shfl_xor(cs0, 16, 64); cs0 += __shfl_xor(cs0, 32, 64);
        cs1 += __shfl_xor(cs1, 16, 64); cs1 += __shfl_xor(cs1, 32, 64);
        cs2 += __shfl_xor(cs2, 16, 64); cs2 += __shfl_xor(cs2, 32, 64);
        cs3 += __shfl_xor(cs3, 16, 64); cs3 += __shfl_xor(cs3, 32, 64);
        const float cw = (hi == 0) ? cs0 : (hi == 1) ? cs1 : (hi == 2) ? cs2 : cs3;
        colpart[wr][wc * 64 + hi * 16 + lo] = cw;
    }
    __syncthreads();

    if (t < BM) {
        psum[(size_t)bx * BS + rowBase + t] = rowpart[0][t] + rowpart[1][t];
        if (!diag)
            psum[(size_t)by * BS + colBase + t] = colpart[0][t] + colpart[1][t];
    }
}

// ---------------------------------------------------------------------------
// 3) Per-row: total = sum_cb psum, pe = -(targ - 20 - log total); block
//    partials of w*pe and w; also writes y_true (f32). 32 blocks x 256.
// ---------------------------------------------------------------------------
__global__ __launch_bounds__(256) void reduce_rows_kernel(const float* __restrict__ psum,
                                                          const float* __restrict__ targ,
                                                          const int* __restrict__ mask,
                                                          float* __restrict__ partials,
                                                          float* __restrict__ ytrue_out) {
    const int t = threadIdx.x;
    const int row = blockIdx.x * 256 + t;

    float total = 0.f;
#pragma unroll 8
    for (int cb = 0; cb < 64; ++cb) total += psum[(size_t)cb * BS + row];

    const float pe = -(targ[row] - 20.0f - logf(total));
    const float w = 1.0f - (float)mask[row & (HALF - 1)];
    ytrue_out[row] = (float)((row < HALF) ? row + HALF : row - HALF);

    float a = w * pe, b = w;
#pragma unroll
    for (int off = 32; off > 0; off >>= 1) {
        a += __shfl_down(a, off, 64);
        b += __shfl_down(b, off, 64);
    }
    __shared__ float ra[4], rb[4];
    if ((t & 63) == 0) { ra[t >> 6] = a; rb[t >> 6] = b; }
    __syncthreads();
    if (t == 0) {
        partials[blockIdx.x] = ra[0] + ra[1] + ra[2] + ra[3];
        partials[32 + blockIdx.x] = rb[0] + rb[1] + rb[2] + rb[3];
    }
}

__global__ void loss_kernel(const float* __restrict__ partials,
                            float* __restrict__ loss_out) {
    if (threadIdx.x == 0) {
        float A = 0.f, B = 0.f;
        for (int i = 0; i < 32; ++i) { A += partials[i]; B += partials[32 + i]; }
        loss_out[0] = A / B;
    }
}

// ---------------------------------------------------------------------------
extern "C" void kernel_launch(void* const* d_in, const int* in_sizes, int n_in,
                              void* d_out, int out_size, void* d_ws, size_t ws_size,
                              hipStream_t stream) {
    const float* f1 = (const float*)d_in[0];
    const float* f2 = (const float*)d_in[1];
    const int* mask = (const int*)d_in[2];
    float* out = (float*)d_out;

    unsigned short* nb = (unsigned short*)d_ws;                          // 16 MB
    float* psum = (float*)((char*)d_ws + (size_t)BS * DIM * 2);          // 2 MB
    float* targ = psum + (size_t)64 * BS;                                // 32 KB
    float* partials = targ + BS;                                         // 256 B
    float* logits = out + 1;
    float* ytrue_out = out + 1 + (size_t)BS * BS;

    norm_kernel<<<BS, 256, 0, stream>>>(f1, f2, nb);

    const int ntri = (BS / BM) * (BS / BM + 1) / 2;   // 2080
    gemm_kernel<<<ntri, 256, 0, stream>>>(nb, logits, psum, targ);

    reduce_rows_kernel<<<BS / 256, 256, 0, stream>>>(psum, targ, mask, partials, ytrue_out);
    loss_kernel<<<1, 64, 0, stream>>>(partials, out);
}